// Round 2
// baseline (340.847 us; speedup 1.0000x reference)
//
#include <hip/hip_runtime.h>
#include <hip/hip_bf16.h>
#include <math.h>

// Problem constants
#define BB 256
#define TT 512
#define EE 128
#define HH 128
#define NC 4
#define MM (BB * TT)   // 131072 rows of the input GEMM

typedef __bf16 bf16x8 __attribute__((ext_vector_type(8)));
typedef __bf16 bf16x4 __attribute__((ext_vector_type(4)));
typedef float  f32x4  __attribute__((ext_vector_type(4)));

// ---------------------------------------------------------------------------
// Kernel 1: x_proj[m,h] = sum_e emb[x[m],e] * W_ih[h,e] + b_ih[h] + b_hh[h]
// fp32 inputs. Split-bf16 GEMM: V = hi + lo (each bf16); A*W ~= Ah*Wh + Al*Wh
// + Ah*Wl (residual ~2^-17 rel). MFMA 16x16x32 bf16, fp32 accumulate.
// 1024 blocks x 256 threads; block tile 128(M) x 128(N), K=128.
// ---------------------------------------------------------------------------
template <typename XPT>
__global__ __launch_bounds__(256, 1) void embed_gemm(
    const int* __restrict__ x, const float* __restrict__ emb,
    const float* __restrict__ Wih, const float* __restrict__ bih,
    const float* __restrict__ bhh, XPT* __restrict__ xpout)
{
    const int tid = threadIdx.x;
    const int m0  = blockIdx.x * 128;

    const int LDA = 136;  // bf16 units: 128 + 8 pad (272B rows, 16B aligned)
    __shared__ __bf16 Ah[128 * 136];
    __shared__ __bf16 Al[128 * 136];
    __shared__ __bf16 Wh[128 * 136];
    __shared__ __bf16 Wl[128 * 136];
    __shared__ float  bias_s[128];

    // Stage + split. 16384 floats each for A and W; float4 per thread-iter.
#pragma unroll
    for (int it = 0; it < 16; ++it) {
        int c   = it * 256 + tid;   // 0..4095 float4-chunks
        int row = c >> 5;           // 0..127
        int seg = c & 31;           // float4 index within row

        float4 wv = ((const float4*)Wih)[c];
        bf16x4 wh, wl;
        wh[0] = (__bf16)wv.x; wl[0] = (__bf16)(wv.x - (float)wh[0]);
        wh[1] = (__bf16)wv.y; wl[1] = (__bf16)(wv.y - (float)wh[1]);
        wh[2] = (__bf16)wv.z; wl[2] = (__bf16)(wv.z - (float)wh[2]);
        wh[3] = (__bf16)wv.w; wl[3] = (__bf16)(wv.w - (float)wh[3]);
        *(bf16x4*)&Wh[row * LDA + seg * 4] = wh;
        *(bf16x4*)&Wl[row * LDA + seg * 4] = wl;

        int gi = x[m0 + row];
        float4 av = ((const float4*)(emb + (size_t)gi * 128))[seg];
        bf16x4 ah, al;
        ah[0] = (__bf16)av.x; al[0] = (__bf16)(av.x - (float)ah[0]);
        ah[1] = (__bf16)av.y; al[1] = (__bf16)(av.y - (float)ah[1]);
        ah[2] = (__bf16)av.z; al[2] = (__bf16)(av.z - (float)ah[2]);
        ah[3] = (__bf16)av.w; al[3] = (__bf16)(av.w - (float)ah[3]);
        *(bf16x4*)&Ah[row * LDA + seg * 4] = ah;
        *(bf16x4*)&Al[row * LDA + seg * 4] = al;
    }
    if (tid < 128) bias_s[tid] = bih[tid] + bhh[tid];
    __syncthreads();

    const int lane = tid & 63, wid = tid >> 6;
    const int col  = lane & 15, quad = lane >> 4;

    f32x4 acc[2][8];
#pragma unroll
    for (int mt = 0; mt < 2; ++mt)
#pragma unroll
        for (int nt = 0; nt < 8; ++nt) acc[mt][nt] = f32x4{0.f, 0.f, 0.f, 0.f};

#pragma unroll
    for (int kk = 0; kk < 4; ++kk) {  // K steps of 32
        bf16x8 afh[2], afl[2];
#pragma unroll
        for (int mt = 0; mt < 2; ++mt) {
            int ro = (wid * 32 + mt * 16 + col) * LDA + kk * 32 + quad * 8;
            afh[mt] = *(const bf16x8*)&Ah[ro];
            afl[mt] = *(const bf16x8*)&Al[ro];
        }
#pragma unroll
        for (int nt = 0; nt < 8; ++nt) {
            int ro = (nt * 16 + col) * LDA + kk * 32 + quad * 8;
            bf16x8 wfh = *(const bf16x8*)&Wh[ro];
            bf16x8 wfl = *(const bf16x8*)&Wl[ro];
#pragma unroll
            for (int mt = 0; mt < 2; ++mt) {
                acc[mt][nt] = __builtin_amdgcn_mfma_f32_16x16x32_bf16(afh[mt], wfh, acc[mt][nt], 0, 0, 0);
                acc[mt][nt] = __builtin_amdgcn_mfma_f32_16x16x32_bf16(afl[mt], wfh, acc[mt][nt], 0, 0, 0);
                acc[mt][nt] = __builtin_amdgcn_mfma_f32_16x16x32_bf16(afh[mt], wfl, acc[mt][nt], 0, 0, 0);
            }
        }
    }

    // Epilogue: C/D layout col=lane&15, row=(lane>>4)*4+reg  [verified m89/m91]
#pragma unroll
    for (int mt = 0; mt < 2; ++mt) {
#pragma unroll
        for (int nt = 0; nt < 8; ++nt) {
            int m = m0 + wid * 32 + mt * 16 + quad * 4;
            int n = nt * 16 + col;
            float bs = bias_s[n];
#pragma unroll
            for (int r = 0; r < 4; ++r)
                xpout[(size_t)(m + r) * 128 + n] = (XPT)(acc[mt][nt][r] + bs);
        }
    }
}

// ---------------------------------------------------------------------------
// Kernel 2: sequential scan  h = tanh(x_proj[t] + W_hh @ h)   (512 steps)
// One block per batch element (256 blocks = 1/CU), 256 threads (4 waves).
// Thread (half,i): W_hh[i][64*half..+64) in 64 VGPRs (fp32); LDS partial-sum
// combine + tanh. x_proj streamed via 8-step LDS double buffer.
// ---------------------------------------------------------------------------
template <typename XPT>
__global__ __launch_bounds__(256, 1) void rnn_scan(
    const XPT* __restrict__ xp, const float* __restrict__ Whh,
    const float* __restrict__ h0, float* __restrict__ hlast)
{
    const int b    = blockIdx.x;
    const int tid  = threadIdx.x;
    const int half = tid >> 7;   // which 64-wide K-slice
    const int i    = tid & 127;  // output element

    __shared__ float h_s[128];
    __shared__ float part[256];
    __shared__ float xbuf[2][8 * 128];

    // W_hh half-row into registers (fp32)
    float w[64];
    const float* wr = Whh + i * 128 + half * 64;
#pragma unroll
    for (int c = 0; c < 16; ++c) {
        float4 v = ((const float4*)wr)[c];
        w[c * 4 + 0] = v.x; w[c * 4 + 1] = v.y;
        w[c * 4 + 2] = v.z; w[c * 4 + 3] = v.w;
    }

    if (tid < 128) h_s[tid] = h0[b * 128 + tid];

    const XPT* xpb = xp + (size_t)b * (TT * 128);
    {   // preload window 0 (8 steps x 128 = 1024 elems; 4 per thread)
        const XPT* s = xpb + tid * 4;
        float4 v;
        v.x = (float)s[0]; v.y = (float)s[1]; v.z = (float)s[2]; v.w = (float)s[3];
        *(float4*)&xbuf[0][tid * 4] = v;
    }
    __syncthreads();

    int cb = 0;
    for (int tw = 0; tw < TT; tw += 8) {
        // prefetch next window into registers (stored to LDS after this window)
        float4 pre = {0.f, 0.f, 0.f, 0.f};
        const bool hasnext = (tw + 8) < TT;
        if (hasnext) {
            const XPT* s = xpb + (size_t)(tw + 8) * 128 + tid * 4;
            pre.x = (float)s[0]; pre.y = (float)s[1]; pre.z = (float)s[2]; pre.w = (float)s[3];
        }
#pragma unroll
        for (int ts = 0; ts < 8; ++ts) {
            const float* hh = &h_s[half * 64];
            float a0 = 0.f, a1 = 0.f;
#pragma unroll
            for (int j = 0; j < 64; j += 2) {
                a0 += w[j] * hh[j];
                a1 += w[j + 1] * hh[j + 1];
            }
            part[tid] = a0 + a1;
            __syncthreads();                    // partials visible; h_s reads done
            if (tid < 128) {
                float v = xbuf[cb][ts * 128 + i] + part[i] + part[i + 128];
                h_s[i] = tanhf(v);
            }
            __syncthreads();                    // new h visible before next dot
        }
        if (hasnext) *(float4*)&xbuf[cb ^ 1][tid * 4] = pre;
        cb ^= 1;
        __syncthreads();
    }
    if (tid < 128) hlast[b * 128 + tid] = h_s[tid];
}

// ---------------------------------------------------------------------------
// Kernel 3: MLP head. hidden = relu(h @ W1^T + b1) [256]; logits = hidden @ W2^T + b2 [4]
// One block per batch row. Also writes last_hidden to d_out.
// ---------------------------------------------------------------------------
__global__ __launch_bounds__(256, 1) void mlp_head(
    const float* __restrict__ hlast, const float* __restrict__ W1,
    const float* __restrict__ b1, const float* __restrict__ W2,
    const float* __restrict__ b2, float* __restrict__ out)
{
    const int b = blockIdx.x, tid = threadIdx.x;
    __shared__ float h_row[128];
    __shared__ float hid[256];

    if (tid < 128) {
        float hv = hlast[b * 128 + tid];
        h_row[tid] = hv;
        out[1024 + b * 128 + tid] = hv;   // last_hidden output (fp32)
    }
    __syncthreads();

    // hidden[tid] = relu(b1[tid] + sum_k W1[tid][k] * h[k]); W1 from L2 (shared across blocks)
    {
        float acc = b1[tid];
        const float4* wrow = (const float4*)(W1 + (size_t)tid * 128);
#pragma unroll
        for (int k4 = 0; k4 < 32; ++k4) {
            float4 wv = wrow[k4];
            acc += wv.x * h_row[k4 * 4 + 0] + wv.y * h_row[k4 * 4 + 1]
                 + wv.z * h_row[k4 * 4 + 2] + wv.w * h_row[k4 * 4 + 3];
        }
        hid[tid] = fmaxf(acc, 0.f);
    }
    __syncthreads();

    // logits: wave w -> class w; 64-lane strided partials + shuffle reduce
    const int wv = tid >> 6, lane = tid & 63;
    float s = 0.f;
#pragma unroll
    for (int q = 0; q < 4; ++q)
        s += hid[q * 64 + lane] * W2[wv * 256 + q * 64 + lane];
#pragma unroll
    for (int off = 32; off > 0; off >>= 1) s += __shfl_down(s, off);
    if (lane == 0) out[b * 4 + wv] = s + b2[wv];
}

// ---------------------------------------------------------------------------
extern "C" void kernel_launch(void* const* d_in, const int* in_sizes, int n_in,
                              void* d_out, int out_size, void* d_ws, size_t ws_size,
                              hipStream_t stream)
{
    const int*   x   = (const int*)d_in[0];
    const float* h0  = (const float*)d_in[1];
    const float* emb = (const float*)d_in[2];
    const float* Wih = (const float*)d_in[3];
    const float* Whh = (const float*)d_in[4];
    const float* bih = (const float*)d_in[5];
    const float* bhh = (const float*)d_in[6];
    const float* W1  = (const float*)d_in[7];
    const float* b1  = (const float*)d_in[8];
    const float* W2  = (const float*)d_in[9];
    const float* b2  = (const float*)d_in[10];
    float* out = (float*)d_out;

    const size_t xp_f32_bytes = (size_t)MM * 128 * sizeof(float);   // 64 MB
    const size_t hl_bytes     = (size_t)BB * 128 * sizeof(float);   // 128 KB

    if (ws_size >= xp_f32_bytes + hl_bytes) {
        float* xpw = (float*)d_ws;
        float* hl  = (float*)((char*)d_ws + xp_f32_bytes);
        embed_gemm<float><<<MM / 128, 256, 0, stream>>>(x, emb, Wih, bih, bhh, xpw);
        rnn_scan<float><<<BB, 256, 0, stream>>>(xpw, Whh, h0, hl);
        mlp_head<<<BB, 256, 0, stream>>>(hl, W1, b1, W2, b2, out);
    } else {
        // Fallback: bf16 x_proj storage (32 MB) if workspace is small
        __bf16* xpw = (__bf16*)d_ws;
        float*  hl  = (float*)((char*)d_ws + (size_t)MM * 128 * sizeof(__bf16));
        embed_gemm<__bf16><<<MM / 128, 256, 0, stream>>>(x, emb, Wih, bih, bhh, xpw);
        rnn_scan<__bf16><<<BB, 256, 0, stream>>>(xpw, Whh, h0, hl);
        mlp_head<<<BB, 256, 0, stream>>>(hl, W1, b1, W2, b2, out);
    }
}

// Round 4
// 293.794 us; speedup vs baseline: 1.1602x; 1.1602x over previous
//
#include <hip/hip_runtime.h>
#include <hip/hip_bf16.h>
#include <math.h>

// Problem constants
#define BB 256
#define TT 512
#define EE 128
#define HH 128
#define NC 4
#define MM (BB * TT)   // 131072 rows of the input GEMM

typedef __bf16 bf16x8 __attribute__((ext_vector_type(8)));
typedef __bf16 bf16x4 __attribute__((ext_vector_type(4)));
typedef float  f32x4  __attribute__((ext_vector_type(4)));
typedef float  f32x2  __attribute__((ext_vector_type(2)));

// Branch-free tanh: 1 - 2/(1+e^{2x}) with e^{2x} = exp2(2*log2e*x).
// v_exp_f32 + v_rcp_f32; exact at saturation, ~1e-6 rel error.
__device__ __forceinline__ float fast_tanh(float x) {
    float t = __builtin_amdgcn_exp2f(x * 2.885390081777927f);
    return 1.f - 2.f * __builtin_amdgcn_rcpf(1.f + t);
}

// ---------------------------------------------------------------------------
// Kernel 1: x_proj[m,h] = sum_e emb[x[m],e] * W_ih[h,e] + b_ih[h] + b_hh[h]
// fp32 inputs. Split-bf16 GEMM (3 MFMA passes: AhWh + AlWh + AhWl).
// 1024 blocks x 256 threads; block tile 128(M) x 128(N), K=128.
// launch_bounds(256,2): 2 blocks/CU to overlap staging latency.
// ---------------------------------------------------------------------------
template <typename XPT>
__global__ __launch_bounds__(256, 2) void embed_gemm(
    const int* __restrict__ x, const float* __restrict__ emb,
    const float* __restrict__ Wih, const float* __restrict__ bih,
    const float* __restrict__ bhh, XPT* __restrict__ xpout)
{
    const int tid = threadIdx.x;
    const int m0  = blockIdx.x * 128;

    const int LDA = 136;  // bf16 units: 128 + 8 pad (272B rows, 16B aligned)
    __shared__ __bf16 Ah[128 * 136];
    __shared__ __bf16 Al[128 * 136];
    __shared__ __bf16 Wh[128 * 136];
    __shared__ __bf16 Wl[128 * 136];
    __shared__ float  bias_s[128];

    // Stage + split. 16384 floats each for A and W; float4 per thread-iter.
#pragma unroll
    for (int it = 0; it < 16; ++it) {
        int c   = it * 256 + tid;   // 0..4095 float4-chunks
        int row = c >> 5;           // 0..127
        int seg = c & 31;           // float4 index within row

        float4 wv = ((const float4*)Wih)[c];
        bf16x4 wh, wl;
        wh[0] = (__bf16)wv.x; wl[0] = (__bf16)(wv.x - (float)wh[0]);
        wh[1] = (__bf16)wv.y; wl[1] = (__bf16)(wv.y - (float)wh[1]);
        wh[2] = (__bf16)wv.z; wl[2] = (__bf16)(wv.z - (float)wh[2]);
        wh[3] = (__bf16)wv.w; wl[3] = (__bf16)(wv.w - (float)wh[3]);
        *(bf16x4*)&Wh[row * LDA + seg * 4] = wh;
        *(bf16x4*)&Wl[row * LDA + seg * 4] = wl;

        int gi = x[m0 + row];
        float4 av = ((const float4*)(emb + (size_t)gi * 128))[seg];
        bf16x4 ah, al;
        ah[0] = (__bf16)av.x; al[0] = (__bf16)(av.x - (float)ah[0]);
        ah[1] = (__bf16)av.y; al[1] = (__bf16)(av.y - (float)ah[1]);
        ah[2] = (__bf16)av.z; al[2] = (__bf16)(av.z - (float)ah[2]);
        ah[3] = (__bf16)av.w; al[3] = (__bf16)(av.w - (float)ah[3]);
        *(bf16x4*)&Ah[row * LDA + seg * 4] = ah;
        *(bf16x4*)&Al[row * LDA + seg * 4] = al;
    }
    if (tid < 128) bias_s[tid] = bih[tid] + bhh[tid];
    __syncthreads();

    const int lane = tid & 63, wid = tid >> 6;
    const int col  = lane & 15, quad = lane >> 4;

    f32x4 acc[2][8];
#pragma unroll
    for (int mt = 0; mt < 2; ++mt)
#pragma unroll
        for (int nt = 0; nt < 8; ++nt) acc[mt][nt] = f32x4{0.f, 0.f, 0.f, 0.f};

#pragma unroll
    for (int kk = 0; kk < 4; ++kk) {  // K steps of 32
        bf16x8 afh[2], afl[2];
#pragma unroll
        for (int mt = 0; mt < 2; ++mt) {
            int ro = (wid * 32 + mt * 16 + col) * LDA + kk * 32 + quad * 8;
            afh[mt] = *(const bf16x8*)&Ah[ro];
            afl[mt] = *(const bf16x8*)&Al[ro];
        }
#pragma unroll
        for (int nt = 0; nt < 8; ++nt) {
            int ro = (nt * 16 + col) * LDA + kk * 32 + quad * 8;
            bf16x8 wfh = *(const bf16x8*)&Wh[ro];
            bf16x8 wfl = *(const bf16x8*)&Wl[ro];
#pragma unroll
            for (int mt = 0; mt < 2; ++mt) {
                acc[mt][nt] = __builtin_amdgcn_mfma_f32_16x16x32_bf16(afh[mt], wfh, acc[mt][nt], 0, 0, 0);
                acc[mt][nt] = __builtin_amdgcn_mfma_f32_16x16x32_bf16(afl[mt], wfh, acc[mt][nt], 0, 0, 0);
                acc[mt][nt] = __builtin_amdgcn_mfma_f32_16x16x32_bf16(afh[mt], wfl, acc[mt][nt], 0, 0, 0);
            }
        }
    }

    // Epilogue: C/D layout col=lane&15, row=(lane>>4)*4+reg  [verified m89/m91]
#pragma unroll
    for (int mt = 0; mt < 2; ++mt) {
#pragma unroll
        for (int nt = 0; nt < 8; ++nt) {
            int m = m0 + wid * 32 + mt * 16 + quad * 4;
            int n = nt * 16 + col;
            float bs = bias_s[n];
#pragma unroll
            for (int r = 0; r < 4; ++r)
                xpout[(size_t)(m + r) * 128 + n] = (XPT)(acc[mt][nt][r] + bs);
        }
    }
}

// ---------------------------------------------------------------------------
// Kernel 2: sequential scan  h = tanh(x_proj[t] + W_hh @ h)   (512 steps)
// One block per batch element (256 blocks = 1/CU), 256 threads = 4 waves.
// Wave q owns K-slice [32q,32q+32): reads ONLY that h range from LDS
// (8 broadcast ds_read_b128), lane l computes outputs {l, l+64} over the
// slice with float2 (v_pk_fma_f32) math. Partials in part[4][128]
// (conflict-free b32). x_proj arrives via an 8-deep per-thread register
// ring of global loads (no LDS, off the critical path).
// ---------------------------------------------------------------------------
template <typename XPT>
__global__ __launch_bounds__(256, 1) void rnn_scan(
    const XPT* __restrict__ xp, const float* __restrict__ Whh,
    const float* __restrict__ h0, float* __restrict__ hlast)
{
    const int b    = blockIdx.x;
    const int tid  = threadIdx.x;
    const int q    = tid >> 6;       // wave id = K-slice
    const int lane = tid & 63;

    __shared__ float h_s[128];
    __shared__ float part[4 * 128];

    // Weights: rows lane and lane+64, K-slice [32q, 32q+32), as float2 pairs
    f32x2 w0[16], w1[16];
    {
        const float* r0 = Whh + (size_t)lane * 128 + q * 32;
        const float* r1 = Whh + (size_t)(lane + 64) * 128 + q * 32;
#pragma unroll
        for (int c = 0; c < 8; ++c) {
            float4 v0 = ((const float4*)r0)[c];
            float4 v1 = ((const float4*)r1)[c];
            w0[c * 2 + 0] = f32x2{v0.x, v0.y}; w0[c * 2 + 1] = f32x2{v0.z, v0.w};
            w1[c * 2 + 0] = f32x2{v1.x, v1.y}; w1[c * 2 + 1] = f32x2{v1.z, v1.w};
        }
    }

    if (tid < 128) h_s[tid] = h0[b * 128 + tid];

    // x_proj register ring: 8 steps ahead (threads 0..127 only)
    const XPT* xpb = xp + (size_t)b * (TT * 128);
    float xv[8];
#pragma unroll
    for (int s = 0; s < 8; ++s)
        xv[s] = (tid < 128) ? (float)xpb[s * 128 + tid] : 0.f;
    __syncthreads();

    for (int tw = 0; tw < TT; tw += 8) {
#pragma unroll
        for (int ts = 0; ts < 8; ++ts) {
            // dot: all 4 waves, distinct K-slices, broadcast h reads
            f32x2 a0 = f32x2{0.f, 0.f}, a1 = f32x2{0.f, 0.f};
            const float* hq = &h_s[q * 32];
#pragma unroll
            for (int u = 0; u < 8; ++u) {
                float4 h4 = *(const float4*)&hq[u * 4];
                f32x2 hA = f32x2{h4.x, h4.y};
                f32x2 hB = f32x2{h4.z, h4.w};
                a0 += w0[u * 2 + 0] * hA;  a0 += w0[u * 2 + 1] * hB;
                a1 += w1[u * 2 + 0] * hA;  a1 += w1[u * 2 + 1] * hB;
            }
            part[q * 128 + lane]      = a0[0] + a0[1];
            part[q * 128 + 64 + lane] = a1[0] + a1[1];
            __syncthreads();
            if (tid < 128) {
                float s = (part[tid] + part[128 + tid])
                        + (part[256 + tid] + part[384 + tid]);
                h_s[tid] = fast_tanh(s + xv[ts]);
                // refill ring slot for step tw+8+ts
                if (tw + 8 < TT)
                    xv[ts] = (float)xpb[(size_t)(tw + 8 + ts) * 128 + tid];
            }
            __syncthreads();
        }
    }
    if (tid < 128) hlast[b * 128 + tid] = h_s[tid];
}

// ---------------------------------------------------------------------------
// Kernel 3: MLP head. hidden = relu(h @ W1^T + b1) [256]; logits = hidden @ W2^T + b2 [4]
// One block per batch row. Also writes last_hidden to d_out.
// ---------------------------------------------------------------------------
__global__ __launch_bounds__(256, 2) void mlp_head(
    const float* __restrict__ hlast, const float* __restrict__ W1,
    const float* __restrict__ b1, const float* __restrict__ W2,
    const float* __restrict__ b2, float* __restrict__ out)
{
    const int b = blockIdx.x, tid = threadIdx.x;
    __shared__ float h_row[128];
    __shared__ float hid[256];

    if (tid < 128) {
        float hv = hlast[b * 128 + tid];
        h_row[tid] = hv;
        out[1024 + b * 128 + tid] = hv;   // last_hidden output (fp32)
    }
    __syncthreads();

    // hidden[tid] = relu(b1[tid] + sum_k W1[tid][k] * h[k]); W1 from L2
    {
        float acc = b1[tid];
        const float4* wrow = (const float4*)(W1 + (size_t)tid * 128);
#pragma unroll
        for (int k4 = 0; k4 < 32; ++k4) {
            float4 wv = wrow[k4];
            acc += wv.x * h_row[k4 * 4 + 0] + wv.y * h_row[k4 * 4 + 1]
                 + wv.z * h_row[k4 * 4 + 2] + wv.w * h_row[k4 * 4 + 3];
        }
        hid[tid] = fmaxf(acc, 0.f);
    }
    __syncthreads();

    // logits: wave w -> class w; 64-lane strided partials + shuffle reduce
    const int wv = tid >> 6, lane = tid & 63;
    float s = 0.f;
#pragma unroll
    for (int qq = 0; qq < 4; ++qq)
        s += hid[qq * 64 + lane] * W2[wv * 256 + qq * 64 + lane];
#pragma unroll
    for (int off = 32; off > 0; off >>= 1) s += __shfl_down(s, off);
    if (lane == 0) out[b * 4 + wv] = s + b2[wv];
}

// ---------------------------------------------------------------------------
extern "C" void kernel_launch(void* const* d_in, const int* in_sizes, int n_in,
                              void* d_out, int out_size, void* d_ws, size_t ws_size,
                              hipStream_t stream)
{
    const int*   x   = (const int*)d_in[0];
    const float* h0  = (const float*)d_in[1];
    const float* emb = (const float*)d_in[2];
    const float* Wih = (const float*)d_in[3];
    const float* Whh = (const float*)d_in[4];
    const float* bih = (const float*)d_in[5];
    const float* bhh = (const float*)d_in[6];
    const float* W1  = (const float*)d_in[7];
    const float* b1  = (const float*)d_in[8];
    const float* W2  = (const float*)d_in[9];
    const float* b2  = (const float*)d_in[10];
    float* out = (float*)d_out;

    const size_t xp_f32_bytes = (size_t)MM * 128 * sizeof(float);   // 64 MB
    const size_t hl_bytes     = (size_t)BB * 128 * sizeof(float);   // 128 KB

    if (ws_size >= xp_f32_bytes + hl_bytes) {
        float* xpw = (float*)d_ws;
        float* hl  = (float*)((char*)d_ws + xp_f32_bytes);
        embed_gemm<float><<<MM / 128, 256, 0, stream>>>(x, emb, Wih, bih, bhh, xpw);
        rnn_scan<float><<<BB, 256, 0, stream>>>(xpw, Whh, h0, hl);
        mlp_head<<<BB, 256, 0, stream>>>(hl, W1, b1, W2, b2, out);
    } else {
        // Fallback: bf16 x_proj storage (32 MB) if workspace is small
        __bf16* xpw = (__bf16*)d_ws;
        float*  hl  = (float*)((char*)d_ws + (size_t)MM * 128 * sizeof(__bf16));
        embed_gemm<__bf16><<<MM / 128, 256, 0, stream>>>(x, emb, Wih, bih, bhh, xpw);
        rnn_scan<__bf16><<<BB, 256, 0, stream>>>(xpw, Whh, h0, hl);
        mlp_head<<<BB, 256, 0, stream>>>(hl, W1, b1, W2, b2, out);
    }
}

// Round 5
// 272.667 us; speedup vs baseline: 1.2500x; 1.0775x over previous
//
#include <hip/hip_runtime.h>
#include <hip/hip_bf16.h>
#include <math.h>

// Problem constants
#define BB 256
#define TT 512
#define EE 128
#define HH 128
#define NC 4
#define MM (BB * TT)   // 131072 rows of the input GEMM

typedef __bf16 bf16x8 __attribute__((ext_vector_type(8)));
typedef __bf16 bf16x4 __attribute__((ext_vector_type(4)));
typedef float  f32x4  __attribute__((ext_vector_type(4)));
typedef float  f32x2  __attribute__((ext_vector_type(2)));

// Branch-free tanh: 1 - 2/(1+e^{2x}) with e^{2x} = exp2(2*log2e*x).
__device__ __forceinline__ float fast_tanh(float x) {
    float t = __builtin_amdgcn_exp2f(x * 2.885390081777927f);
    return 1.f - 2.f * __builtin_amdgcn_rcpf(1.f + t);
}

// ---------------------------------------------------------------------------
// Kernel 1: x_proj[m,h] = sum_e emb[x[m],e] * W_ih[h,e] + b_ih[h] + b_hh[h]
// Split-bf16 GEMM (AhWh + AlWh + AhWl). K processed in 2 halves of 64 with
// half-size LDS buffers (~74 KB total) so 2 blocks/CU actually fit
// (previous 140 KB forced 1 block/CU and serialized everything).
// ---------------------------------------------------------------------------
template <typename XPT>
__global__ __launch_bounds__(256, 2) void embed_gemm(
    const int* __restrict__ x, const float* __restrict__ emb,
    const float* __restrict__ Wih, const float* __restrict__ bih,
    const float* __restrict__ bhh, XPT* __restrict__ xpout)
{
    const int tid = threadIdx.x;
    const int m0  = blockIdx.x * 128;

    const int LDA = 72;  // bf16 units per 64-wide half row (144 B, 16B-aligned)
    __shared__ __bf16 Ah[128 * 72];
    __shared__ __bf16 Al[128 * 72];
    __shared__ __bf16 Wh[128 * 72];
    __shared__ __bf16 Wl[128 * 72];
    __shared__ float  bias_s[128];
    __shared__ int    gix[128];

    if (tid < 128) {
        gix[tid]    = x[m0 + tid];
        bias_s[tid] = bih[tid] + bhh[tid];
    }

    const int lane = tid & 63, wid = tid >> 6;
    const int col  = lane & 15, quad = lane >> 4;

    f32x4 acc[2][8];
#pragma unroll
    for (int mt = 0; mt < 2; ++mt)
#pragma unroll
        for (int nt = 0; nt < 8; ++nt) acc[mt][nt] = f32x4{0.f, 0.f, 0.f, 0.f};

    __syncthreads();   // gix/bias visible

#pragma unroll
    for (int half = 0; half < 2; ++half) {
        // Stage this K-half: 2048 float4 chunks each for A and W.
#pragma unroll
        for (int it = 0; it < 8; ++it) {
            int c   = it * 256 + tid;   // 0..2047
            int row = c >> 4;           // 0..127
            int seg = c & 15;           // float4 within the 64-col half

            float4 wv = ((const float4*)Wih)[row * 32 + half * 16 + seg];
            bf16x4 wh, wl;
            wh[0] = (__bf16)wv.x; wl[0] = (__bf16)(wv.x - (float)wh[0]);
            wh[1] = (__bf16)wv.y; wl[1] = (__bf16)(wv.y - (float)wh[1]);
            wh[2] = (__bf16)wv.z; wl[2] = (__bf16)(wv.z - (float)wh[2]);
            wh[3] = (__bf16)wv.w; wl[3] = (__bf16)(wv.w - (float)wh[3]);
            *(bf16x4*)&Wh[row * LDA + seg * 4] = wh;
            *(bf16x4*)&Wl[row * LDA + seg * 4] = wl;

            int gi = gix[row];
            float4 av = ((const float4*)emb)[(size_t)gi * 32 + half * 16 + seg];
            bf16x4 ah, al;
            ah[0] = (__bf16)av.x; al[0] = (__bf16)(av.x - (float)ah[0]);
            ah[1] = (__bf16)av.y; al[1] = (__bf16)(av.y - (float)ah[1]);
            ah[2] = (__bf16)av.z; al[2] = (__bf16)(av.z - (float)ah[2]);
            ah[3] = (__bf16)av.w; al[3] = (__bf16)(av.w - (float)ah[3]);
            *(bf16x4*)&Ah[row * LDA + seg * 4] = ah;
            *(bf16x4*)&Al[row * LDA + seg * 4] = al;
        }
        __syncthreads();   // staged data visible

#pragma unroll
        for (int kk = 0; kk < 2; ++kk) {  // K steps of 32 within the half
            bf16x8 afh[2], afl[2];
#pragma unroll
            for (int mt = 0; mt < 2; ++mt) {
                int ro = (wid * 32 + mt * 16 + col) * LDA + kk * 32 + quad * 8;
                afh[mt] = *(const bf16x8*)&Ah[ro];
                afl[mt] = *(const bf16x8*)&Al[ro];
            }
#pragma unroll
            for (int nt = 0; nt < 8; ++nt) {
                int ro = (nt * 16 + col) * LDA + kk * 32 + quad * 8;
                bf16x8 wfh = *(const bf16x8*)&Wh[ro];
                bf16x8 wfl = *(const bf16x8*)&Wl[ro];
#pragma unroll
                for (int mt = 0; mt < 2; ++mt) {
                    acc[mt][nt] = __builtin_amdgcn_mfma_f32_16x16x32_bf16(afh[mt], wfh, acc[mt][nt], 0, 0, 0);
                    acc[mt][nt] = __builtin_amdgcn_mfma_f32_16x16x32_bf16(afl[mt], wfh, acc[mt][nt], 0, 0, 0);
                    acc[mt][nt] = __builtin_amdgcn_mfma_f32_16x16x32_bf16(afh[mt], wfl, acc[mt][nt], 0, 0, 0);
                }
            }
        }
        if (half == 0) __syncthreads();   // MFMA reads done before restage
    }

    // Epilogue: C/D layout col=lane&15, row=(lane>>4)*4+reg  [verified m89/m91]
#pragma unroll
    for (int mt = 0; mt < 2; ++mt) {
#pragma unroll
        for (int nt = 0; nt < 8; ++nt) {
            int m = m0 + wid * 32 + mt * 16 + quad * 4;
            int n = nt * 16 + col;
            float bs = bias_s[n];
#pragma unroll
            for (int r = 0; r < 4; ++r)
                xpout[(size_t)(m + r) * 128 + n] = (XPT)(acc[mt][nt][r] + bs);
        }
    }
}

// ---------------------------------------------------------------------------
// Kernel 2: sequential scan  h = tanh(x_proj[t] + W_hh @ h)   (512 steps)
// One block per batch element (256 blocks = 1/CU), 256 threads = 4 waves.
// Wave q owns K-slice [32q,32q+32); lane l computes outputs {l, l+64}.
// W_hh slice pinned in VGPRs via inline-asm (round-4 counters showed
// VGPR_Count=52 -> compiler was NOT keeping the 64 weights resident and
// re-fetched them every step on the serial critical path).
// ---------------------------------------------------------------------------
template <typename XPT>
__global__ __launch_bounds__(256, 1) void rnn_scan(
    const XPT* __restrict__ xp, const float* __restrict__ Whh,
    const float* __restrict__ h0, float* __restrict__ hlast)
{
    const int b    = blockIdx.x;
    const int tid  = threadIdx.x;
    const int q    = tid >> 6;       // wave id = K-slice
    const int lane = tid & 63;

    __shared__ float h_s[128];
    __shared__ float part[4 * 128];

    // Weights: rows lane and lane+64, K-slice [32q, 32q+32), as float4s.
    f32x4 wA[8], wB[8];
    {
        const float* r0 = Whh + (size_t)lane * 128 + q * 32;
        const float* r1 = Whh + (size_t)(lane + 64) * 128 + q * 32;
#pragma unroll
        for (int c = 0; c < 8; ++c) {
            wA[c] = *(const f32x4*)(r0 + c * 4);
            wB[c] = *(const f32x4*)(r1 + c * 4);
        }
    }
    // Pin: asm result cannot be rematerialized -> weights stay in VGPRs.
#pragma unroll
    for (int c = 0; c < 8; ++c)
        asm volatile("" : "+v"(wA[c]), "+v"(wB[c]));

    if (tid < 128) h_s[tid] = h0[b * 128 + tid];

    // x_proj register ring: 8 steps ahead (threads 0..127 only)
    const XPT* xpb = xp + (size_t)b * (TT * 128);
    float xv[8];
#pragma unroll
    for (int s = 0; s < 8; ++s)
        xv[s] = (tid < 128) ? (float)xpb[s * 128 + tid] : 0.f;
    __syncthreads();

    for (int tw = 0; tw < TT; tw += 8) {
#pragma unroll
        for (int ts = 0; ts < 8; ++ts) {
            // broadcast reads of this wave's h slice (8 ds_read_b128)
            const float* hq = &h_s[q * 32];
            f32x4 h4[8];
#pragma unroll
            for (int u = 0; u < 8; ++u) h4[u] = *(const f32x4*)&hq[u * 4];

            f32x4 aA = f32x4{0.f, 0.f, 0.f, 0.f};
            f32x4 aB = f32x4{0.f, 0.f, 0.f, 0.f};
#pragma unroll
            for (int u = 0; u < 8; ++u) {
                aA += wA[u] * h4[u];
                aB += wB[u] * h4[u];
            }
            part[q * 128 + lane]      = (aA[0] + aA[1]) + (aA[2] + aA[3]);
            part[q * 128 + 64 + lane] = (aB[0] + aB[1]) + (aB[2] + aB[3]);
            __syncthreads();
            if (tid < 128) {
                float s = (part[tid] + part[128 + tid])
                        + (part[256 + tid] + part[384 + tid]);
                h_s[tid] = fast_tanh(s + xv[ts]);
                // refill ring slot for step tw+8+ts
                if (tw + 8 < TT)
                    xv[ts] = (float)xpb[(size_t)(tw + 8 + ts) * 128 + tid];
            }
            __syncthreads();
        }
    }
    if (tid < 128) hlast[b * 128 + tid] = h_s[tid];
}

// ---------------------------------------------------------------------------
// Kernel 3: MLP head. hidden = relu(h @ W1^T + b1) [256]; logits = hidden @ W2^T + b2 [4]
// One block per batch row. Also writes last_hidden to d_out.
// ---------------------------------------------------------------------------
__global__ __launch_bounds__(256, 2) void mlp_head(
    const float* __restrict__ hlast, const float* __restrict__ W1,
    const float* __restrict__ b1, const float* __restrict__ W2,
    const float* __restrict__ b2, float* __restrict__ out)
{
    const int b = blockIdx.x, tid = threadIdx.x;
    __shared__ float h_row[128];
    __shared__ float hid[256];

    if (tid < 128) {
        float hv = hlast[b * 128 + tid];
        h_row[tid] = hv;
        out[1024 + b * 128 + tid] = hv;   // last_hidden output (fp32)
    }
    __syncthreads();

    // hidden[tid] = relu(b1[tid] + sum_k W1[tid][k] * h[k]); W1 from L2
    {
        float acc = b1[tid];
        const float4* wrow = (const float4*)(W1 + (size_t)tid * 128);
#pragma unroll
        for (int k4 = 0; k4 < 32; ++k4) {
            float4 wv = wrow[k4];
            acc += wv.x * h_row[k4 * 4 + 0] + wv.y * h_row[k4 * 4 + 1]
                 + wv.z * h_row[k4 * 4 + 2] + wv.w * h_row[k4 * 4 + 3];
        }
        hid[tid] = fmaxf(acc, 0.f);
    }
    __syncthreads();

    // logits: wave w -> class w; 64-lane strided partials + shuffle reduce
    const int wv = tid >> 6, lane = tid & 63;
    float s = 0.f;
#pragma unroll
    for (int qq = 0; qq < 4; ++qq)
        s += hid[qq * 64 + lane] * W2[wv * 256 + qq * 64 + lane];
#pragma unroll
    for (int off = 32; off > 0; off >>= 1) s += __shfl_down(s, off);
    if (lane == 0) out[b * 4 + wv] = s + b2[wv];
}

// ---------------------------------------------------------------------------
extern "C" void kernel_launch(void* const* d_in, const int* in_sizes, int n_in,
                              void* d_out, int out_size, void* d_ws, size_t ws_size,
                              hipStream_t stream)
{
    const int*   x   = (const int*)d_in[0];
    const float* h0  = (const float*)d_in[1];
    const float* emb = (const float*)d_in[2];
    const float* Wih = (const float*)d_in[3];
    const float* Whh = (const float*)d_in[4];
    const float* bih = (const float*)d_in[5];
    const float* bhh = (const float*)d_in[6];
    const float* W1  = (const float*)d_in[7];
    const float* b1  = (const float*)d_in[8];
    const float* W2  = (const float*)d_in[9];
    const float* b2  = (const float*)d_in[10];
    float* out = (float*)d_out;

    const size_t xp_f32_bytes = (size_t)MM * 128 * sizeof(float);   // 64 MB
    const size_t hl_bytes     = (size_t)BB * 128 * sizeof(float);   // 128 KB

    if (ws_size >= xp_f32_bytes + hl_bytes) {
        float* xpw = (float*)d_ws;
        float* hl  = (float*)((char*)d_ws + xp_f32_bytes);
        embed_gemm<float><<<MM / 128, 256, 0, stream>>>(x, emb, Wih, bih, bhh, xpw);
        rnn_scan<float><<<BB, 256, 0, stream>>>(xpw, Whh, h0, hl);
        mlp_head<<<BB, 256, 0, stream>>>(hl, W1, b1, W2, b2, out);
    } else {
        // Fallback: bf16 x_proj storage (32 MB) if workspace is small
        __bf16* xpw = (__bf16*)d_ws;
        float*  hl  = (float*)((char*)d_ws + (size_t)MM * 128 * sizeof(__bf16));
        embed_gemm<__bf16><<<MM / 128, 256, 0, stream>>>(x, emb, Wih, bih, bhh, xpw);
        rnn_scan<__bf16><<<BB, 256, 0, stream>>>(xpw, Whh, h0, hl);
        mlp_head<<<BB, 256, 0, stream>>>(hl, W1, b1, W2, b2, out);
    }
}